// Round 2
// baseline (1762.747 us; speedup 1.0000x reference)
//
#include <hip/hip_runtime.h>
#include <math.h>

#define BB 4
#define LL 2048
#define HH 8
#define EE 64
#define TM 64
#define TN 64
#define SH 72   // fp16 LDS row stride: 36 dwords -> 4-bank offset per row (m97 pattern)

typedef _Float16 half4v __attribute__((ext_vector_type(4)));
typedef _Float16 half8v __attribute__((ext_vector_type(8)));
typedef float floatx4 __attribute__((ext_vector_type(4)));

static constexpr float SCALE = 0.125f;                    // 1/sqrt(64)
static constexpr float LN3 = 1.0986122886681098f;
static constexpr float INV_SQRT_2PI = 0.3989422804014327f;
static constexpr size_t NMAT = (size_t)BB * HH * LL * LL;
static constexpr size_t SERIES_BASE = (size_t)BB * LL * HH * EE;
static constexpr size_t PRIOR_BASE = SERIES_BASE + NMAT;
static constexpr size_t SIG_BASE = PRIOR_BASE + NMAT;

// ============================================================================
// Kernel A: pure streaming writes — prior (full), sig (full), series zero
// region (j >= tile-causal boundary). No barriers, 8 blocks/CU, grid-stride
// by wave. Non-temporal stores: this 1.28 GB is never re-read.
// ============================================================================
__global__ __launch_bounds__(256, 8)
void prior_sig_fill(const float* __restrict__ sgg, float* __restrict__ out) {
  const int lane = threadIdx.x & 63;
  const int wv = (blockIdx.x << 2) | (threadIdx.x >> 6);   // global wave id
  const int nw = gridDim.x << 2;
  const int totalRows = BB * HH * LL;
  for (int row = wv; row < totalRows; row += nw) {
    const int bh = row >> 11;          // row / LL
    const int i = row & (LL - 1);
    const int b = bh >> 3, h = bh & 7;
    // wave-uniform sigma load (broadcast) + transform, redundant per lane
    float sg = sgg[((size_t)b * LL + i) * HH + h];
    float sd = 1.0f / (1.0f + __expf(-5.0f * sg)) + 1e-5f;
    float sv = expm1f(sd * LN3);       // 3^sd - 1, cancellation-safe
    float iv = INV_SQRT_2PI / sv;
    float c2 = 0.5f / (sv * sv);
    const size_t roff = ((size_t)bh * LL + i) * LL;
    const floatx4 s4 = {sv, sv, sv, sv};
    const float fi = (float)i;
#pragma unroll
    for (int it = 0; it < 8; ++it) {
      int j = (it << 8) + (lane << 2);           // 64 lanes x float4 = 256 cols
      float d0 = fi - (float)j;
      float d1 = d0 - 1.0f, d2 = d0 - 2.0f, d3 = d0 - 3.0f;
      floatx4 pr;
      pr.x = iv * __expf(-d0 * d0 * c2);
      pr.y = iv * __expf(-d1 * d1 * c2);
      pr.z = iv * __expf(-d2 * d2 * c2);
      pr.w = iv * __expf(-d3 * d3 * c2);
      __builtin_nontemporal_store(pr, (floatx4*)&out[PRIOR_BASE + roff + j]);
      __builtin_nontemporal_store(s4, (floatx4*)&out[SIG_BASE + roff + j]);
    }
    // series zero region: j in [ (i/64 + 1)*64, LL )
    const int jz = ((i >> 6) + 1) << 6;
    const floatx4 z = {0.f, 0.f, 0.f, 0.f};
    for (int j = jz + (lane << 2); j < LL; j += 256) {
      __builtin_nontemporal_store(z, (floatx4*)&out[SERIES_BASE + roff + j]);
    }
  }
}

// ============================================================================
// Kernel B: attention — causal series tiles + V only. Structure unchanged
// from the verified 1714 µs kernel, minus prior/sig/zero-fill (moved to A).
// Series stores made non-temporal.
// ============================================================================
__global__ __launch_bounds__(256, 2)
void anomaly_attn(const float* __restrict__ qg,
                  const float* __restrict__ kg,
                  const float* __restrict__ vg,
                  float* __restrict__ out) {
  __shared__ __attribute__((aligned(16))) _Float16 Qh[TM * SH];
  __shared__ __attribute__((aligned(16))) _Float16 Kh[TN * SH];
  __shared__ __attribute__((aligned(16))) _Float16 Vt[EE * SH];  // transposed: [e][j]
  __shared__ __attribute__((aligned(16))) _Float16 Ph[TM * SH];

  const int t = threadIdx.x;
  const int lane = t & 63;
  const int w = t >> 6;          // wave id 0..3 -> rows w*16..w*16+15
  const int quad = lane >> 4;    // 0..3
  const int l15 = lane & 15;
  const int bh = blockIdx.y;
  const int b = bh >> 3, h = bh & 7;
  const float4* q4 = (const float4*)qg;
  const float4* k4 = (const float4*)kg;
  const float4* v4 = (const float4*)vg;

  for (int half = 0; half < 2; ++half) {
    const int rt = half ? (31 - (int)blockIdx.x) : (int)blockIdx.x;
    const int i0 = rt * TM;
    const int nt = rt + 1;       // causal j-tiles
    __syncthreads();             // protect LDS from previous half's readers

    // ---- stage Q (fp32 -> fp16 LDS, row-major) ----
#pragma unroll
    for (int it = 0; it < 4; ++it) {
      int idx = t + 256 * it;
      int r = idx >> 4, c = idx & 15;
      float4 qv = q4[(((size_t)b * LL + i0 + r) * HH + h) * 16 + c];
      half4v hq = {(_Float16)qv.x, (_Float16)qv.y, (_Float16)qv.z, (_Float16)qv.w};
      *(half4v*)&Qh[r * SH + c * 4] = hq;
    }

    // ================= pass 1: row sums of exp(scale*s) =================
    float lsum[4] = {0.f, 0.f, 0.f, 0.f};
    for (int jt = 0; jt < nt; ++jt) {
      const int j0 = jt * TN;
      __syncthreads();             // prev tile's Kh readers done
#pragma unroll
      for (int it = 0; it < 4; ++it) {
        int idx = t + 256 * it;
        int r = idx >> 4, c = idx & 15;
        float4 kv = k4[(((size_t)b * LL + j0 + r) * HH + h) * 16 + c];
        half4v hk = {(_Float16)kv.x, (_Float16)kv.y, (_Float16)kv.z, (_Float16)kv.w};
        *(half4v*)&Kh[r * SH + c * 4] = hk;
      }
      __syncthreads();
      floatx4 acc[4] = {{0.f, 0.f, 0.f, 0.f}, {0.f, 0.f, 0.f, 0.f},
                        {0.f, 0.f, 0.f, 0.f}, {0.f, 0.f, 0.f, 0.f}};
#pragma unroll
      for (int ks = 0; ks < 2; ++ks) {
        half8v a = *(half8v*)&Qh[(w * 16 + l15) * SH + ks * 32 + quad * 8];
#pragma unroll
        for (int f = 0; f < 4; ++f) {
          half8v bf = *(half8v*)&Kh[(f * 16 + l15) * SH + ks * 32 + quad * 8];
          acc[f] = __builtin_amdgcn_mfma_f32_16x16x32_f16(a, bf, acc[f], 0, 0, 0);
        }
      }
#pragma unroll
      for (int f = 0; f < 4; ++f) {
        int j = j0 + f * 16 + l15;        // C col = lane&15
#pragma unroll
        for (int r = 0; r < 4; ++r) {
          int i = i0 + w * 16 + quad * 4 + r;  // C row = quad*4+reg
          lsum[r] += (j <= i) ? __expf(acc[f][r] * SCALE) : 0.f;
        }
      }
    }
#pragma unroll
    for (int r = 0; r < 4; ++r) {
      lsum[r] += __shfl_xor(lsum[r], 1);
      lsum[r] += __shfl_xor(lsum[r], 2);
      lsum[r] += __shfl_xor(lsum[r], 4);
      lsum[r] += __shfl_xor(lsum[r], 8);
    }
    float linv[4];
#pragma unroll
    for (int r = 0; r < 4; ++r) linv[r] = 1.0f / lsum[r];

    // ================= pass 2: series + PV =================
    floatx4 Oacc[4] = {{0.f, 0.f, 0.f, 0.f}, {0.f, 0.f, 0.f, 0.f},
                       {0.f, 0.f, 0.f, 0.f}, {0.f, 0.f, 0.f, 0.f}};
    for (int jt = 0; jt < nt; ++jt) {
      const int j0 = jt * TN;
      __syncthreads();             // prev tile's Ph/Vt/Kh readers done
#pragma unroll
      for (int it = 0; it < 4; ++it) {
        int idx = t + 256 * it;
        int r = idx >> 4, c = idx & 15;
        float4 kv = k4[(((size_t)b * LL + j0 + r) * HH + h) * 16 + c];
        half4v hk = {(_Float16)kv.x, (_Float16)kv.y, (_Float16)kv.z, (_Float16)kv.w};
        *(half4v*)&Kh[r * SH + c * 4] = hk;
      }
      // V staged transposed: thread (tx=e-group, ty=j-group) does 4x4 micro-transpose
      {
        const int tx = t & 15, ty = t >> 4;
        float4 vv[4];
#pragma unroll
        for (int rr = 0; rr < 4; ++rr)
          vv[rr] = v4[(((size_t)b * LL + j0 + ty * 4 + rr) * HH + h) * 16 + tx];
#pragma unroll
        for (int c = 0; c < 4; ++c) {
          float e0 = c == 0 ? vv[0].x : c == 1 ? vv[0].y : c == 2 ? vv[0].z : vv[0].w;
          float e1 = c == 0 ? vv[1].x : c == 1 ? vv[1].y : c == 2 ? vv[1].z : vv[1].w;
          float e2 = c == 0 ? vv[2].x : c == 1 ? vv[2].y : c == 2 ? vv[2].z : vv[2].w;
          float e3 = c == 0 ? vv[3].x : c == 1 ? vv[3].y : c == 2 ? vv[3].z : vv[3].w;
          half4v hv = {(_Float16)e0, (_Float16)e1, (_Float16)e2, (_Float16)e3};
          *(half4v*)&Vt[(tx * 4 + c) * SH + ty * 4] = hv;
        }
      }
      __syncthreads();
      floatx4 acc[4] = {{0.f, 0.f, 0.f, 0.f}, {0.f, 0.f, 0.f, 0.f},
                        {0.f, 0.f, 0.f, 0.f}, {0.f, 0.f, 0.f, 0.f}};
#pragma unroll
      for (int ks = 0; ks < 2; ++ks) {
        half8v a = *(half8v*)&Qh[(w * 16 + l15) * SH + ks * 32 + quad * 8];
#pragma unroll
        for (int f = 0; f < 4; ++f) {
          half8v bf = *(half8v*)&Kh[(f * 16 + l15) * SH + ks * 32 + quad * 8];
          acc[f] = __builtin_amdgcn_mfma_f32_16x16x32_f16(a, bf, acc[f], 0, 0, 0);
        }
      }
      // P = exp(s*scale)*linv (already normalized) -> Ph fp16, C->A layout transform
#pragma unroll
      for (int f = 0; f < 4; ++f) {
        int j = j0 + f * 16 + l15;
#pragma unroll
        for (int r = 0; r < 4; ++r) {
          int i = i0 + w * 16 + quad * 4 + r;
          float p = (j <= i) ? __expf(acc[f][r] * SCALE) * linv[r] : 0.f;
          Ph[(w * 16 + quad * 4 + r) * SH + f * 16 + l15] = (_Float16)p;
        }
      }
      __syncthreads();
      // series tile store: coalesced b128 readback -> 2x float4 (non-temporal)
#pragma unroll
      for (int rnd = 0; rnd < 2; ++rnd) {
        int idx = t + 256 * rnd;
        int r = idx >> 3, c8 = idx & 7;
        half8v p = *(half8v*)&Ph[r * SH + c8 * 8];
        floatx4 lo = {(float)p[0], (float)p[1], (float)p[2], (float)p[3]};
        floatx4 hi = {(float)p[4], (float)p[5], (float)p[6], (float)p[7]};
        size_t off = SERIES_BASE + ((size_t)bh * LL + i0 + r) * LL + j0 + c8 * 8;
        __builtin_nontemporal_store(lo, (floatx4*)&out[off]);
        __builtin_nontemporal_store(hi, (floatx4*)&out[off + 4]);
      }
      // PV: O += P * V  (A = Ph rows, B = Vt rows)
#pragma unroll
      for (int ks = 0; ks < 2; ++ks) {
        half8v a = *(half8v*)&Ph[(w * 16 + l15) * SH + ks * 32 + quad * 8];
#pragma unroll
        for (int f = 0; f < 4; ++f) {
          half8v bv = *(half8v*)&Vt[(f * 16 + l15) * SH + ks * 32 + quad * 8];
          Oacc[f] = __builtin_amdgcn_mfma_f32_16x16x32_f16(a, bv, Oacc[f], 0, 0, 0);
        }
      }
    }
    // ---- V output (already normalized) ----
#pragma unroll
    for (int f = 0; f < 4; ++f) {
#pragma unroll
      for (int r = 0; r < 4; ++r) {
        int i = i0 + w * 16 + quad * 4 + r;
        out[(((size_t)b * LL + i) * HH + h) * EE + f * 16 + l15] = Oacc[f][r];
      }
    }
  }
}

extern "C" void kernel_launch(void* const* d_in, const int* in_sizes, int n_in,
                              void* d_out, int out_size, void* d_ws, size_t ws_size,
                              hipStream_t stream) {
  const float* q = (const float*)d_in[0];
  const float* k = (const float*)d_in[1];
  const float* v = (const float*)d_in[2];
  const float* sg = (const float*)d_in[3];
  float* out = (float*)d_out;
  // A: streaming prior/sig/series-zeros — 2048 blocks, 8/CU, barrier-free
  prior_sig_fill<<<dim3(2048), 256, 0, stream>>>(sg, out);
  // B: attention — causal series + V, strip-paired row tiles
  dim3 grid(LL / TM / 2, BB * HH);  // 16 x 32 = 512 blocks
  anomaly_attn<<<grid, 256, 0, stream>>>(q, k, v, out);
}